// Round 6
// baseline (8913.966 us; speedup 1.0000x reference)
//
#include <hip/hip_runtime.h>
#include <hip/hip_bf16.h>

#define B_  32
#define A_  128
#define T_  64
#define N_  4096        // B_*A_
#define HS  256
#define ES  32
#define RS  64
#define KX  832         // 64 (r) + 512 (e) + 256 (h)
#define GD  1024        // 4*HS
#define NKT 26          // KX/32

typedef __attribute__((ext_vector_type(8))) short bf8_t;            // 8 x bf16
typedef __attribute__((ext_vector_type(8))) unsigned short u16x8;
typedef __attribute__((ext_vector_type(4))) float f4_t;             // mfma acc
typedef __attribute__((ext_vector_type(2))) float f2_t;

__device__ __forceinline__ unsigned short f2bf(float x) {
  union { float f; unsigned u; } v; v.f = x;
  unsigned u = v.u;
  u += 0x7fffu + ((u >> 16) & 1u);     // round-to-nearest-even
  return (unsigned short)(u >> 16);
}
__device__ __forceinline__ float sigm(float x) { return 1.f / (1.f + __expf(-x)); }

__device__ __forceinline__ void gload16(const void* g, void* l) {
  __builtin_amdgcn_global_load_lds((const __attribute__((address_space(1))) void*)g,
                                   (__attribute__((address_space(3))) void*)l, 16, 0, 0);
}

// ---- Wc (permuted: row j = 64*nb+16*g+q <-> orig g*256+nb*16+q) + fused bias
__global__ void k_wcat(const float* __restrict__ W_ih, const float* __restrict__ W_hh,
                       const float* __restrict__ b_ih, const float* __restrict__ b_hh,
                       unsigned short* __restrict__ Wc, float* __restrict__ bsum) {
  int i = blockIdx.x * 256 + threadIdx.x;
  if (i < GD * KX) {
    int mp = i / KX, k = i - mp * KX;
    int nb = mp >> 6, rem = mp & 63, g = rem >> 4, q = rem & 15;
    int mo = g * 256 + nb * 16 + q;
    float v = (k < 576) ? W_ih[mo * 576 + k] : W_hh[mo * 256 + (k - 576)];
    Wc[i] = f2bf(v);
  } else if (i < GD * KX + GD) {
    int j = i - GD * KX;
    int nb = j >> 6, rem = j & 63, g = rem >> 4, q = rem & 15;
    int mo = g * 256 + nb * 16 + q;
    bsum[j] = b_ih[mo] + b_hh[mo];
  }
}

// ---- collapsed head: Whead[o][320] = (Wo @ W_p2) @ W_p   (5 blocks x 320 thr)
__global__ __launch_bounds__(320) void k_head(
    const float* __restrict__ W_p, const float* __restrict__ b_p,
    const float* __restrict__ W_p2, const float* __restrict__ b_p2,
    const float* __restrict__ W_mu, const float* __restrict__ b_mu,
    const float* __restrict__ W_sd, const float* __restrict__ b_sd,
    const float* __restrict__ W_cr, const float* __restrict__ b_cr,
    float* __restrict__ Whead, float* __restrict__ bhead) {
  int o = blockIdx.x, tid = threadIdx.x;
  __shared__ float to[64];
  const float* Wo = (o < 2) ? W_mu + o * 32 : (o < 4) ? W_sd + (o - 2) * 32 : W_cr;
  if (tid < 64) {
    float a = 0.f;
    #pragma unroll 8
    for (int c = 0; c < 32; ++c) a += Wo[c] * W_p2[c * 64 + tid];
    to[tid] = a;
  }
  __syncthreads();
  float a = 0.f;
  #pragma unroll 8
  for (int j = 0; j < 64; ++j) a += to[j] * W_p[j * 320 + tid];
  Whead[o * 320 + tid] = a;
  if (tid == 0) {
    float b0 = (o < 2) ? b_mu[o] : (o < 4) ? b_sd[o - 2] : b_cr[0];
    float acc = b0;
    for (int c = 0; c < 32; ++c) acc += Wo[c] * b_p2[c];
    for (int j = 0; j < 64; ++j) acc += to[j] * b_p[j];
    bhead[o] = acc;
  }
}

// ---- head finalize for rows n0..n0+8: add r(ts)-part + bhead, nonlinearity,
// write out(ts), zero the scratch rows. (shared by k_social prologue & k_fin)
__device__ __forceinline__ void head_finalize(
    const float* __restrict__ data, const float* __restrict__ W_r,
    const float* __restrict__ b_r, const float* __restrict__ Whead,
    const float* __restrict__ bhead, float* __restrict__ hscr,
    float* __restrict__ out, int n0, int ts, int tid) {
  int r8 = tid >> 5, ln = tid & 31;
  int n = n0 + r8;
  float x0 = data[(n * T_ + ts) * 2 + 0];
  float x1 = data[(n * T_ + ts) * 2 + 1];
  float s0 = 0.f, s1 = 0.f, s2 = 0.f, s3 = 0.f, s4 = 0.f;
  #pragma unroll
  for (int l2 = 0; l2 < 2; ++l2) {
    int l = ln + 32 * l2;
    float rv = fmaxf(x0 * W_r[l * 2] + x1 * W_r[l * 2 + 1] + b_r[l], 0.f);
    s0 += rv * Whead[0 * 320 + l];
    s1 += rv * Whead[1 * 320 + l];
    s2 += rv * Whead[2 * 320 + l];
    s3 += rv * Whead[3 * 320 + l];
    s4 += rv * Whead[4 * 320 + l];
  }
  #pragma unroll
  for (int off = 16; off; off >>= 1) {
    s0 += __shfl_xor(s0, off);
    s1 += __shfl_xor(s1, off);
    s2 += __shfl_xor(s2, off);
    s3 += __shfl_xor(s3, off);
    s4 += __shfl_xor(s4, off);
  }
  if (ln == 0) {
    float* hp = hscr + (size_t)n * 5;
    out[(n * T_ + ts) * 2 + 0] = hp[0] + s0 + bhead[0];
    out[(n * T_ + ts) * 2 + 1] = hp[1] + s1 + bhead[1];
    out[N_ * T_ * 2 + (n * T_ + ts) * 2 + 0] = __expf(hp[2] + s2 + bhead[2]);
    out[N_ * T_ * 2 + (n * T_ + ts) * 2 + 1] = __expf(hp[3] + s3 + bhead[3]);
    out[N_ * T_ * 4 + n * T_ + ts] = tanhf(hp[4] + s4 + bhead[4]);
    hp[0] = 0.f; hp[1] = 0.f; hp[2] = 0.f; hp[3] = 0.f; hp[4] = 0.f;
  }
}

// ---- social + per-step housekeeping.
// Block (b, ig) owns rows n0 = b*128+ig*8 .. +8. Prologue: finalize head(t-1),
// zero hWnext slice, write r(t) -> Xcur. Then outer-product social -> Xcur e.
__global__ __launch_bounds__(256) void k_social(
    const float* __restrict__ data, const float* __restrict__ hWcur,
    float* __restrict__ hWnext, const float* __restrict__ b_e,
    unsigned short* __restrict__ Xcur, float* __restrict__ hscr_prev,
    const float* __restrict__ Whead, const float* __restrict__ bhead,
    const float* __restrict__ W_r, const float* __restrict__ b_r,
    float* __restrict__ out, int t) {
  int b  = blockIdx.x >> 4;
  int ig = blockIdx.x & 15;
  int n0 = b * A_ + ig * 8;
  __shared__ float sx[A_], sy[A_];
  __shared__ float shw2[64 * 64];     // [jp][c][sub]  16 KB
  __shared__ float smx[8][64][8];     // [r][jp][gx*2+sub]  16 KB
  __shared__ float smy[8][64][8];     // [r][jp][gy*2+sub]  16 KB
  int tid = threadIdx.x;
  if (tid < A_) {
    sx[tid] = data[((b * A_ + tid) * T_ + t) * 2 + 0];
    sy[tid] = data[((b * A_ + tid) * T_ + t) * 2 + 1];
  }
  for (int i = tid; i < A_ * ES; i += 256) {
    int j = i >> 5, c = i & 31;
    shw2[(j >> 1) * 64 + c * 2 + (j & 1)] = hWcur[b * A_ * ES + i];
  }
  // housekeeping (no LDS deps): finalize head(t-1), zero hWnext, write r(t)
  if (t > 0)
    head_finalize(data, W_r, b_r, Whead, bhead, hscr_prev, out, n0, t - 1, tid);
  hWnext[(size_t)n0 * ES + tid] = 0.f;
  #pragma unroll
  for (int u = tid; u < 512; u += 256) {
    int rr = u >> 6, l = u & 63;
    int n = n0 + rr;
    float x0 = data[(n * T_ + t) * 2 + 0];
    float x1 = data[(n * T_ + t) * 2 + 1];
    Xcur[(size_t)n * KX + l] =
        f2bf(fmaxf(x0 * W_r[l * 2] + x1 * W_r[l * 2 + 1] + b_r[l], 0.f));
  }
  __syncthreads();

  // phase 1: indicator build (512 units = 8 rows x 64 j-pairs)
  for (int u = tid; u < 512; u += 256) {
    int r = u >> 6, jp = u & 63;
    int irow = ig * 8 + r;
    float xi = sx[irow], yi = sy[irow];
    bool acti = xi >= 0.f;
    float m0[4], m1[4], nn0[4], nn1[4];
    #pragma unroll
    for (int s = 0; s < 2; ++s) {
      int j = jp * 2 + s;
      float xj = sx[j], yj = sy[j];
      bool v = acti && (xj >= 0.f) && (j != irow);
      float dx = xi - xj, dy = yi - yj;
      float* mm = s ? m1 : m0;
      float* nn = s ? nn1 : nn0;
      mm[0] = (v && dx >= 8.f   && dx <= 16.f) ? 1.f : 0.f;
      mm[1] = (v && dx >= 0.f   && dx <= 8.f ) ? 1.f : 0.f;
      mm[2] = (v && dx >= -8.f  && dx <= 0.f ) ? 1.f : 0.f;
      mm[3] = (v && dx >= -16.f && dx <= -8.f) ? 1.f : 0.f;
      nn[0] = (dy >= -16.f && dy <= -8.f) ? 1.f : 0.f;
      nn[1] = (dy >= -8.f  && dy <= 0.f ) ? 1.f : 0.f;
      nn[2] = (dy >= 0.f   && dy <= 8.f ) ? 1.f : 0.f;
      nn[3] = (dy >= 8.f   && dy <= 16.f) ? 1.f : 0.f;
    }
    float4* px = (float4*)&smx[r][jp][0];
    px[0] = (float4){m0[0], m1[0], m0[1], m1[1]};
    px[1] = (float4){m0[2], m1[2], m0[3], m1[3]};
    float4* py = (float4*)&smy[r][jp][0];
    py[0] = (float4){nn0[0], nn1[0], nn0[1], nn1[1]};
    py[1] = (float4){nn0[2], nn1[2], nn0[3], nn1[3]};
  }
  __syncthreads();

  // phase 2: register accumulate, f2 (paired j) math
  int half = tid >> 5;               // row within group
  int lane = tid & 31;               // channel
  f2_t acc[16];
  #pragma unroll
  for (int g = 0; g < 16; ++g) acc[g] = (f2_t){0.f, 0.f};
  #pragma unroll 2
  for (int jp = 0; jp < 64; ++jp) {
    f2_t hv = *(const f2_t*)&shw2[jp * 64 + lane * 2];
    float4 xa = ((const float4*)&smx[half][jp][0])[0];
    float4 xb = ((const float4*)&smx[half][jp][0])[1];
    float4 ya = ((const float4*)&smy[half][jp][0])[0];
    float4 yb = ((const float4*)&smy[half][jp][0])[1];
    f2_t mx[4] = {(f2_t){xa.x, xa.y}, (f2_t){xa.z, xa.w},
                  (f2_t){xb.x, xb.y}, (f2_t){xb.z, xb.w}};
    f2_t p[4]  = {(f2_t){ya.x, ya.y} * hv, (f2_t){ya.z, ya.w} * hv,
                  (f2_t){yb.x, yb.y} * hv, (f2_t){yb.z, yb.w} * hv};
    #pragma unroll
    for (int gy = 0; gy < 4; ++gy)
      #pragma unroll
      for (int gx = 0; gx < 4; ++gx)
        acc[gy * 4 + gx] += mx[gx] * p[gy];
  }

  // epilogue: e -> Xcur at torch-reshape-permuted location
  int irow = ig * 8 + half;
  float be = b_e[lane];
  int hi = irow >> 4;
  int klo = (irow & 15) * ES + lane;
  #pragma unroll
  for (int g = 0; g < 16; ++g) {
    float e = fmaxf(acc[g][0] + acc[g][1] + be, 0.f);
    int a_out = g * 8 + hi;
    Xcur[(b * A_ + a_out) * KX + 64 + klo] = f2bf(e);
  }
}

// ---- gates GEMM (permuted cols) + fused LSTM pointwise + hW/head partials
__global__ __launch_bounds__(256) void k_gemm_lstm(
    const unsigned short* __restrict__ Xcur, const unsigned short* __restrict__ Wc,
    const float* __restrict__ bsum,
    float* __restrict__ cbuf, unsigned short* __restrict__ Xnext,
    const float* __restrict__ W_e, const float* __restrict__ Whead,
    float* __restrict__ hWnext, float* __restrict__ hscr) {
  // union: [ sA0 8K | sB0 4K | sA1 8K | sB1 4K ] (24K)  vs  gtile 128x65 f32 (33.3K)
  __shared__ __align__(16) char smem[33280];
  __shared__ float sbias[64];
  unsigned short* sA0 = (unsigned short*)smem;
  unsigned short* sB0 = (unsigned short*)(smem + 8192);
  unsigned short* sA1 = (unsigned short*)(smem + 12288);
  unsigned short* sB1 = (unsigned short*)(smem + 20480);
  float (*gtile)[65] = (float (*)[65])smem;

  int bid = blockIdx.x;
  int tn = bid & 15, tm = bid >> 4;
  int row0 = tm * 128, col0 = tn * 64;
  int tid = threadIdx.x;
  int lane = tid & 63;
  int w = tid >> 6;
  int wr = w >> 1, wc = w & 1;              // 2x2 waves: 64x32 each
  int lr = lane & 15, lh = lane >> 4;

  if (tid < 64) sbias[tid] = bsum[col0 + tid];

  int srow = tid >> 2, schunk = tid & 3;
  int gch = (schunk ^ ((srow >> 1) & 3)) * 8;
  const unsigned short* gA0 = Xcur + (size_t)(row0 + srow) * KX + gch;
  const unsigned short* gA1 = Xcur + (size_t)(row0 + 64 + srow) * KX + gch;
  const unsigned short* gB  = Wc  + (size_t)(col0 + srow) * KX + gch;

  int swz = (lh ^ ((lr >> 1) & 3)) * 8;
  int aoff[4], boff[2];
  #pragma unroll
  for (int m = 0; m < 4; ++m) aoff[m] = (wr * 64 + m * 16 + lr) * 32 + swz;
  #pragma unroll
  for (int n = 0; n < 2; ++n) boff[n] = (wc * 32 + n * 16 + lr) * 32 + swz;

  f4_t acc[4][2];
  #pragma unroll
  for (int m = 0; m < 4; ++m)
    #pragma unroll
    for (int n = 0; n < 2; ++n) acc[m][n] = (f4_t){0.f, 0.f, 0.f, 0.f};

#define STAGE(pA, pB, kt) do { \
    gload16(gA0 + (kt) * 32, (pA) + tid * 8); \
    gload16(gA1 + (kt) * 32, (pA) + 2048 + tid * 8); \
    gload16(gB  + (kt) * 32, (pB) + tid * 8); \
  } while (0)

#define COMPUTE(pA, pB) do { \
    bf8_t a_[4], b_[2]; \
    _Pragma("unroll") for (int m = 0; m < 4; ++m) a_[m] = *(const bf8_t*)((pA) + aoff[m]); \
    _Pragma("unroll") for (int n = 0; n < 2; ++n) b_[n] = *(const bf8_t*)((pB) + boff[n]); \
    _Pragma("unroll") for (int m = 0; m < 4; ++m) \
      _Pragma("unroll") for (int n = 0; n < 2; ++n) \
        acc[m][n] = __builtin_amdgcn_mfma_f32_16x16x32_bf16(a_[m], b_[n], acc[m][n], 0, 0, 0); \
  } while (0)

  STAGE(sA0, sB0, 0);
  __syncthreads();
  #pragma unroll 1
  for (int kt = 0; kt < NKT; kt += 2) {
    STAGE(sA1, sB1, kt + 1);
    COMPUTE(sA0, sB0);
    __syncthreads();
    if (kt + 2 < NKT) STAGE(sA0, sB0, kt + 2);
    COMPUTE(sA1, sB1);
    __syncthreads();
  }
#undef STAGE
#undef COMPUTE

  int crow = (lane >> 4) * 4, ccol = lane & 15;
  #pragma unroll
  for (int m = 0; m < 4; ++m)
    #pragma unroll
    for (int n = 0; n < 2; ++n)
      #pragma unroll
      for (int j = 0; j < 4; ++j)
        gtile[wr * 64 + m * 16 + crow + j][wc * 32 + n * 16 + ccol] = acc[m][n][j];
  __syncthreads();

  // LSTM pointwise: thread -> row = tid>>1, channels q0..q0+7 (q0 = (tid&1)*8)
  int row = tid >> 1;
  int q0 = (tid & 1) * 8;
  int grow = row0 + row;
  int ch0 = tn * 16 + q0;
  float4* cb = (float4*)(cbuf + (size_t)grow * HS + ch0);
  float4 cv0 = cb[0], cv1 = cb[1];
  float cold[8] = {cv0.x, cv0.y, cv0.z, cv0.w, cv1.x, cv1.y, cv1.z, cv1.w};
  float c2v[8], h2v[8];
  #pragma unroll
  for (int k = 0; k < 8; ++k) {
    int q = q0 + k;
    float ig = gtile[row][q]      + sbias[q];
    float fg = gtile[row][16 + q] + sbias[16 + q];
    float gg = gtile[row][32 + q] + sbias[32 + q];
    float og = gtile[row][48 + q] + sbias[48 + q];
    float c2 = sigm(fg) * cold[k] + sigm(ig) * tanhf(gg);
    c2v[k] = c2;
    h2v[k] = sigm(og) * tanhf(c2);
  }
  cb[0] = (float4){c2v[0], c2v[1], c2v[2], c2v[3]};
  cb[1] = (float4){c2v[4], c2v[5], c2v[6], c2v[7]};
  u16x8 hx;
  #pragma unroll
  for (int k = 0; k < 8; ++k) hx[k] = f2bf(h2v[k]);
  *(u16x8*)(Xnext + (size_t)grow * KX + 576 + ch0) = hx;

  // hW partial: hWnext[grow][c] += sum_k h2[ch0+k] * W_e[c][ch0+k]
  #pragma unroll
  for (int c = 0; c < 32; ++c) {
    const float4* we = (const float4*)(W_e + c * HS + ch0);
    float4 w0 = we[0], w1 = we[1];
    float a = h2v[0]*w0.x + h2v[1]*w0.y + h2v[2]*w0.z + h2v[3]*w0.w
            + h2v[4]*w1.x + h2v[5]*w1.y + h2v[6]*w1.z + h2v[7]*w1.w;
    a += __shfl_xor(a, 1);
    if ((tid & 1) == 0) atomicAdd(hWnext + (size_t)grow * ES + c, a);
  }
  // head partial: hscr[grow][o] += sum_k h2[ch0+k] * Whead[o][64+ch0+k]
  #pragma unroll
  for (int o = 0; o < 5; ++o) {
    const float4* wh = (const float4*)(Whead + o * 320 + 64 + ch0);
    float4 w0 = wh[0], w1 = wh[1];
    float a = h2v[0]*w0.x + h2v[1]*w0.y + h2v[2]*w0.z + h2v[3]*w0.w
            + h2v[4]*w1.x + h2v[5]*w1.y + h2v[6]*w1.z + h2v[7]*w1.w;
    a += __shfl_xor(a, 1);
    if ((tid & 1) == 0) atomicAdd(hscr + (size_t)grow * 5 + o, a);
  }
}

// ---- final head for t=63 (512 blocks x 8 rows)
__global__ __launch_bounds__(256) void k_fin(
    const float* __restrict__ data, const float* __restrict__ W_r,
    const float* __restrict__ b_r, const float* __restrict__ Whead,
    const float* __restrict__ bhead, float* __restrict__ hscr,
    float* __restrict__ out) {
  head_finalize(data, W_r, b_r, Whead, bhead, hscr, out,
                blockIdx.x * 8, T_ - 1, threadIdx.x);
}

extern "C" void kernel_launch(void* const* d_in, const int* in_sizes, int n_in,
                              void* d_out, int out_size, void* d_ws, size_t ws_size,
                              hipStream_t stream) {
  const float* data = (const float*)d_in[0];
  const float* W_r  = (const float*)d_in[2];
  const float* b_r  = (const float*)d_in[3];
  const float* W_e  = (const float*)d_in[4];
  const float* b_e  = (const float*)d_in[5];
  const float* W_ih = (const float*)d_in[6];
  const float* W_hh = (const float*)d_in[7];
  const float* b_ih = (const float*)d_in[8];
  const float* b_hh = (const float*)d_in[9];
  const float* W_p  = (const float*)d_in[10];
  const float* b_p  = (const float*)d_in[11];
  const float* W_p2 = (const float*)d_in[12];
  const float* b_p2 = (const float*)d_in[13];
  const float* W_mu = (const float*)d_in[14];
  const float* b_mu = (const float*)d_in[15];
  const float* W_sd = (const float*)d_in[16];
  const float* b_sd = (const float*)d_in[17];
  const float* W_cr = (const float*)d_in[18];
  const float* b_cr = (const float*)d_in[19];
  float* out = (float*)d_out;

  char* ws = (char*)d_ws;
  float* cbuf  = (float*)(ws);                               // 4 MB
  float* hW0   = (float*)(ws + (4u  << 20));                 // 0.5 MB
  float* hW1   = (float*)(ws + (5u  << 20));                 // 0.5 MB
  unsigned short* Xbf0 = (unsigned short*)(ws + (6u  << 20)); // 6.5 MB
  unsigned short* Xbf1 = (unsigned short*)(ws + (13u << 20)); // 6.5 MB
  unsigned short* Wc   = (unsigned short*)(ws + (20u << 20)); // 1.7 MB
  float* bsum  = (float*)(ws + (22u << 20));                 // 4 KB
  float* Whead = (float*)(ws + (22u << 20) + 8192);          // 6.4 KB
  float* bhead = (float*)(ws + (22u << 20) + 16384);         // 20 B
  float* hscr0 = (float*)(ws + (23u << 20));                 // 80 KB
  float* hscr1 = (float*)(ws + (23u << 20) + (256u << 10));  // 80 KB

  hipMemsetAsync(cbuf, 0, (size_t)N_ * HS * sizeof(float), stream);
  hipMemsetAsync(hW0,  0, (size_t)N_ * ES * sizeof(float), stream);
  hipMemsetAsync(hW1,  0, (size_t)N_ * ES * sizeof(float), stream);
  hipMemsetAsync(Xbf0, 0, (size_t)N_ * KX * sizeof(unsigned short), stream);
  hipMemsetAsync(hscr0, 0, (size_t)N_ * 5 * sizeof(float), stream);
  hipMemsetAsync(hscr1, 0, (size_t)N_ * 5 * sizeof(float), stream);

  k_wcat<<<(GD * KX + GD + 255) / 256, 256, 0, stream>>>(W_ih, W_hh, b_ih, b_hh, Wc, bsum);
  k_head<<<5, 320, 0, stream>>>(W_p, b_p, W_p2, b_p2, W_mu, b_mu, W_sd, b_sd, W_cr, b_cr,
                                Whead, bhead);

  for (int t = 0; t < T_; ++t) {
    float* hWcur  = (t & 1) ? hW1 : hW0;
    float* hWnext = (t & 1) ? hW0 : hW1;
    unsigned short* Xcur  = (t & 1) ? Xbf1 : Xbf0;
    unsigned short* Xnext = (t & 1) ? Xbf0 : Xbf1;
    float* hscr_t    = (t & 1) ? hscr1 : hscr0;
    float* hscr_prev = (t & 1) ? hscr0 : hscr1;
    k_social<<<512, 256, 0, stream>>>(data, hWcur, hWnext, b_e, Xcur, hscr_prev,
                                      Whead, bhead, W_r, b_r, out, t);
    k_gemm_lstm<<<512, 256, 0, stream>>>(Xcur, Wc, bsum, cbuf, Xnext,
                                         W_e, Whead, hWnext, hscr_t);
  }
  k_fin<<<512, 256, 0, stream>>>(data, W_r, b_r, Whead, bhead, hscr1, out);
}

// Round 7
// 2618.657 us; speedup vs baseline: 3.4040x; 3.4040x over previous
//
#include <hip/hip_runtime.h>
#include <hip/hip_bf16.h>

#define B_  32
#define A_  128
#define T_  64
#define N_  4096        // B_*A_
#define HS  256
#define ES  32
#define RS  64
#define KX  832         // 64 (r) + 512 (e) + 256 (h)
#define GD  1024        // 4*HS
#define NKT 26          // KX/32

typedef __attribute__((ext_vector_type(8))) short bf8_t;            // 8 x bf16
typedef __attribute__((ext_vector_type(8))) unsigned short u16x8;
typedef __attribute__((ext_vector_type(4))) float f4_t;             // mfma acc
typedef __attribute__((ext_vector_type(2))) float f2_t;

__device__ __forceinline__ unsigned short f2bf(float x) {
  union { float f; unsigned u; } v; v.f = x;
  unsigned u = v.u;
  u += 0x7fffu + ((u >> 16) & 1u);     // round-to-nearest-even
  return (unsigned short)(u >> 16);
}
__device__ __forceinline__ float bf2f(unsigned short u) {
  union { unsigned u; float f; } v; v.u = ((unsigned)u) << 16; return v.f;
}
__device__ __forceinline__ float sigm(float x) { return 1.f / (1.f + __expf(-x)); }

__device__ __forceinline__ void gload16(const void* g, void* l) {
  __builtin_amdgcn_global_load_lds((const __attribute__((address_space(1))) void*)g,
                                   (__attribute__((address_space(3))) void*)l, 16, 0, 0);
}

// ---- Wc (permuted) + fused bias + bf16 W_e copy
__global__ void k_wcat(const float* __restrict__ W_ih, const float* __restrict__ W_hh,
                       const float* __restrict__ b_ih, const float* __restrict__ b_hh,
                       const float* __restrict__ W_e,
                       unsigned short* __restrict__ Wc, float* __restrict__ bsum,
                       unsigned short* __restrict__ Web) {
  int i = blockIdx.x * 256 + threadIdx.x;
  if (i < GD * KX) {
    int mp = i / KX, k = i - mp * KX;
    int nb = mp >> 6, rem = mp & 63, g = rem >> 4, q = rem & 15;
    int mo = g * 256 + nb * 16 + q;
    float v = (k < 576) ? W_ih[mo * 576 + k] : W_hh[mo * 256 + (k - 576)];
    Wc[i] = f2bf(v);
  } else if (i < GD * KX + GD) {
    int j = i - GD * KX;
    int nb = j >> 6, rem = j & 63, g = rem >> 4, q = rem & 15;
    int mo = g * 256 + nb * 16 + q;
    bsum[j] = b_ih[mo] + b_hh[mo];
  } else if (i < GD * KX + GD + ES * HS) {
    int j2 = i - GD * KX - GD;
    Web[j2] = f2bf(W_e[j2]);
  }
}

// ---- collapsed head: Whead[o][320] = (Wo @ W_p2) @ W_p   (5 blocks x 320 thr)
__global__ __launch_bounds__(320) void k_head(
    const float* __restrict__ W_p, const float* __restrict__ b_p,
    const float* __restrict__ W_p2, const float* __restrict__ b_p2,
    const float* __restrict__ W_mu, const float* __restrict__ b_mu,
    const float* __restrict__ W_sd, const float* __restrict__ b_sd,
    const float* __restrict__ W_cr, const float* __restrict__ b_cr,
    float* __restrict__ Whead, float* __restrict__ bhead) {
  int o = blockIdx.x, tid = threadIdx.x;
  __shared__ float to[64];
  const float* Wo = (o < 2) ? W_mu + o * 32 : (o < 4) ? W_sd + (o - 2) * 32 : W_cr;
  if (tid < 64) {
    float a = 0.f;
    #pragma unroll 8
    for (int c = 0; c < 32; ++c) a += Wo[c] * W_p2[c * 64 + tid];
    to[tid] = a;
  }
  __syncthreads();
  float a = 0.f;
  #pragma unroll 8
  for (int j = 0; j < 64; ++j) a += to[j] * W_p[j * 320 + tid];
  Whead[o * 320 + tid] = a;
  if (tid == 0) {
    float b0 = (o < 2) ? b_mu[o] : (o < 4) ? b_sd[o - 2] : b_cr[0];
    float acc = b0;
    for (int c = 0; c < 32; ++c) acc += Wo[c] * b_p2[c];
    for (int j = 0; j < 64; ++j) acc += to[j] * b_p[j];
    bhead[o] = acc;
  }
}

// ---- head for step ts, rows n0..n0+8. h2(ts) is the bf16 h-part of Xh.
__device__ __forceinline__ void head_fin_dev(
    const float* __restrict__ data, const float* __restrict__ W_r,
    const float* __restrict__ b_r, const float* __restrict__ Whead,
    const float* __restrict__ bhead, const unsigned short* __restrict__ Xh,
    float* __restrict__ out, int n0, int ts, int tid) {
  int r8 = tid >> 5, ln = tid & 31;
  int n = n0 + r8;
  float s0 = 0.f, s1 = 0.f, s2 = 0.f, s3 = 0.f, s4 = 0.f;
  // h-part: this lane covers k = ln*8 .. +8
  u16x8 hv = *(const u16x8*)(Xh + (size_t)n * KX + 576 + ln * 8);
  float hf[8];
  #pragma unroll
  for (int k = 0; k < 8; ++k) hf[k] = bf2f(hv[k]);
  #pragma unroll
  for (int k = 0; k < 8; ++k) {
    int kk = 64 + ln * 8 + k;
    s0 += hf[k] * Whead[0 * 320 + kk];
    s1 += hf[k] * Whead[1 * 320 + kk];
    s2 += hf[k] * Whead[2 * 320 + kk];
    s3 += hf[k] * Whead[3 * 320 + kk];
    s4 += hf[k] * Whead[4 * 320 + kk];
  }
  // r-part
  float x0 = data[(n * T_ + ts) * 2 + 0];
  float x1 = data[(n * T_ + ts) * 2 + 1];
  #pragma unroll
  for (int l2 = 0; l2 < 2; ++l2) {
    int l = ln + 32 * l2;
    float rv = fmaxf(x0 * W_r[l * 2] + x1 * W_r[l * 2 + 1] + b_r[l], 0.f);
    s0 += rv * Whead[0 * 320 + l];
    s1 += rv * Whead[1 * 320 + l];
    s2 += rv * Whead[2 * 320 + l];
    s3 += rv * Whead[3 * 320 + l];
    s4 += rv * Whead[4 * 320 + l];
  }
  #pragma unroll
  for (int off = 16; off; off >>= 1) {
    s0 += __shfl_xor(s0, off);
    s1 += __shfl_xor(s1, off);
    s2 += __shfl_xor(s2, off);
    s3 += __shfl_xor(s3, off);
    s4 += __shfl_xor(s4, off);
  }
  if (ln == 0) {
    out[(n * T_ + ts) * 2 + 0] = s0 + bhead[0];
    out[(n * T_ + ts) * 2 + 1] = s1 + bhead[1];
    out[N_ * T_ * 2 + (n * T_ + ts) * 2 + 0] = __expf(s2 + bhead[2]);
    out[N_ * T_ * 2 + (n * T_ + ts) * 2 + 1] = __expf(s3 + bhead[3]);
    out[N_ * T_ * 4 + n * T_ + ts] = tanhf(s4 + bhead[4]);
  }
}

// ---- social: head(t-1) finalize + r(t) write + hW via MFMA + outer-product e
__global__ __launch_bounds__(256) void k_social(
    const float* __restrict__ data, const unsigned short* __restrict__ Web,
    const float* __restrict__ b_e, unsigned short* __restrict__ Xcur,
    const float* __restrict__ Whead, const float* __restrict__ bhead,
    const float* __restrict__ W_r, const float* __restrict__ b_r,
    float* __restrict__ out, int t) {
  int b  = blockIdx.x >> 4;
  int ig = blockIdx.x & 15;
  int n0 = b * A_ + ig * 8;
  __shared__ float sx[A_], sy[A_];
  __shared__ float shw2[64 * 64];     // [jp][c][sub]  16 KB
  __shared__ float smx[8][64][8];     // 16 KB
  __shared__ float smy[8][64][8];     // 16 KB
  int tid = threadIdx.x;
  if (tid < A_) {
    sx[tid] = data[((b * A_ + tid) * T_ + t) * 2 + 0];
    sy[tid] = data[((b * A_ + tid) * T_ + t) * 2 + 1];
  }
  // head finalize for t-1 (reads h2(t-1) = Xcur h-part, global only)
  if (t > 0)
    head_fin_dev(data, W_r, b_r, Whead, bhead, Xcur, out, n0, t - 1, tid);
  // r(t) -> Xcur rows n0..+8
  for (int u = tid; u < 512; u += 256) {
    int rr = u >> 6, l = u & 63;
    int n = n0 + rr;
    float x0 = data[(n * T_ + t) * 2 + 0];
    float x1 = data[(n * T_ + t) * 2 + 1];
    Xcur[(size_t)n * KX + l] =
        f2bf(fmaxf(x0 * W_r[l * 2] + x1 * W_r[l * 2 + 1] + b_r[l], 0.f));
  }
  // hW = h2 @ W_e^T via MFMA; wave wv handles rows wv*32..+32 of batch b
  {
    int wv = tid >> 6, lane = tid & 63;
    int lr = lane & 15, lh = lane >> 4;
    const unsigned short* a0p = Xcur + (size_t)(b * A_ + wv * 32 + lr) * KX + 576 + lh * 8;
    const unsigned short* a1p = a0p + 16 * KX;
    const unsigned short* b0p = Web + lr * HS + lh * 8;
    const unsigned short* b1p = Web + (16 + lr) * HS + lh * 8;
    f4_t hacc[2][2];
    hacc[0][0] = (f4_t){0.f,0.f,0.f,0.f}; hacc[0][1] = hacc[0][0];
    hacc[1][0] = hacc[0][0];              hacc[1][1] = hacc[0][0];
    #pragma unroll
    for (int kk = 0; kk < 8; ++kk) {
      bf8_t av0 = *(const bf8_t*)(a0p + kk * 32);
      bf8_t av1 = *(const bf8_t*)(a1p + kk * 32);
      bf8_t bv0 = *(const bf8_t*)(b0p + kk * 32);
      bf8_t bv1 = *(const bf8_t*)(b1p + kk * 32);
      hacc[0][0] = __builtin_amdgcn_mfma_f32_16x16x32_bf16(av0, bv0, hacc[0][0], 0, 0, 0);
      hacc[0][1] = __builtin_amdgcn_mfma_f32_16x16x32_bf16(av0, bv1, hacc[0][1], 0, 0, 0);
      hacc[1][0] = __builtin_amdgcn_mfma_f32_16x16x32_bf16(av1, bv0, hacc[1][0], 0, 0, 0);
      hacc[1][1] = __builtin_amdgcn_mfma_f32_16x16x32_bf16(av1, bv1, hacc[1][1], 0, 0, 0);
    }
    int ccol = lane & 15, crow4 = (lane >> 4) * 4;
    #pragma unroll
    for (int m = 0; m < 2; ++m)
      #pragma unroll
      for (int cb = 0; cb < 2; ++cb)
        #pragma unroll
        for (int j = 0; j < 4; ++j) {
          int rr = wv * 32 + m * 16 + crow4 + j;
          int c  = cb * 16 + ccol;
          shw2[(rr >> 1) * 64 + c * 2 + (rr & 1)] = hacc[m][cb][j];
        }
  }
  __syncthreads();

  // phase 1: indicator build (512 units = 8 rows x 64 j-pairs)
  for (int u = tid; u < 512; u += 256) {
    int r = u >> 6, jp = u & 63;
    int irow = ig * 8 + r;
    float xi = sx[irow], yi = sy[irow];
    bool acti = xi >= 0.f;
    float m0[4], m1[4], nn0[4], nn1[4];
    #pragma unroll
    for (int s = 0; s < 2; ++s) {
      int j = jp * 2 + s;
      float xj = sx[j], yj = sy[j];
      bool v = acti && (xj >= 0.f) && (j != irow);
      float dx = xi - xj, dy = yi - yj;
      float* mm = s ? m1 : m0;
      float* nn = s ? nn1 : nn0;
      mm[0] = (v && dx >= 8.f   && dx <= 16.f) ? 1.f : 0.f;
      mm[1] = (v && dx >= 0.f   && dx <= 8.f ) ? 1.f : 0.f;
      mm[2] = (v && dx >= -8.f  && dx <= 0.f ) ? 1.f : 0.f;
      mm[3] = (v && dx >= -16.f && dx <= -8.f) ? 1.f : 0.f;
      nn[0] = (dy >= -16.f && dy <= -8.f) ? 1.f : 0.f;
      nn[1] = (dy >= -8.f  && dy <= 0.f ) ? 1.f : 0.f;
      nn[2] = (dy >= 0.f   && dy <= 8.f ) ? 1.f : 0.f;
      nn[3] = (dy >= 8.f   && dy <= 16.f) ? 1.f : 0.f;
    }
    float4* px = (float4*)&smx[r][jp][0];
    px[0] = (float4){m0[0], m1[0], m0[1], m1[1]};
    px[1] = (float4){m0[2], m1[2], m0[3], m1[3]};
    float4* py = (float4*)&smy[r][jp][0];
    py[0] = (float4){nn0[0], nn1[0], nn0[1], nn1[1]};
    py[1] = (float4){nn0[2], nn1[2], nn0[3], nn1[3]};
  }
  __syncthreads();

  // phase 2: register accumulate, f2 (paired j) math
  int half = tid >> 5;               // row within group
  int lane = tid & 31;               // channel
  f2_t acc[16];
  #pragma unroll
  for (int g = 0; g < 16; ++g) acc[g] = (f2_t){0.f, 0.f};
  #pragma unroll 2
  for (int jp = 0; jp < 64; ++jp) {
    f2_t hv = *(const f2_t*)&shw2[jp * 64 + lane * 2];
    float4 xa = ((const float4*)&smx[half][jp][0])[0];
    float4 xb = ((const float4*)&smx[half][jp][0])[1];
    float4 ya = ((const float4*)&smy[half][jp][0])[0];
    float4 yb = ((const float4*)&smy[half][jp][0])[1];
    f2_t mx[4] = {(f2_t){xa.x, xa.y}, (f2_t){xa.z, xa.w},
                  (f2_t){xb.x, xb.y}, (f2_t){xb.z, xb.w}};
    f2_t p[4]  = {(f2_t){ya.x, ya.y} * hv, (f2_t){ya.z, ya.w} * hv,
                  (f2_t){yb.x, yb.y} * hv, (f2_t){yb.z, yb.w} * hv};
    #pragma unroll
    for (int gy = 0; gy < 4; ++gy)
      #pragma unroll
      for (int gx = 0; gx < 4; ++gx)
        acc[gy * 4 + gx] += mx[gx] * p[gy];
  }

  // epilogue: e -> Xcur at torch-reshape-permuted location
  int irow = ig * 8 + half;
  float be = b_e[lane];
  int hi = irow >> 4;
  int klo = (irow & 15) * ES + lane;
  #pragma unroll
  for (int g = 0; g < 16; ++g) {
    float e = fmaxf(acc[g][0] + acc[g][1] + be, 0.f);
    int a_out = g * 8 + hi;
    Xcur[(b * A_ + a_out) * KX + 64 + klo] = f2bf(e);
  }
}

// ---- gates GEMM (permuted cols) + fused LSTM pointwise
__global__ __launch_bounds__(256) void k_gemm_lstm(
    const unsigned short* __restrict__ Xcur, const unsigned short* __restrict__ Wc,
    const float* __restrict__ bsum,
    float* __restrict__ cbuf, unsigned short* __restrict__ Xnext) {
  __shared__ __align__(16) char smem[33280];
  __shared__ float sbias[64];
  unsigned short* sA0 = (unsigned short*)smem;
  unsigned short* sB0 = (unsigned short*)(smem + 8192);
  unsigned short* sA1 = (unsigned short*)(smem + 12288);
  unsigned short* sB1 = (unsigned short*)(smem + 20480);
  float (*gtile)[65] = (float (*)[65])smem;

  int bid = blockIdx.x;
  int tn = bid & 15, tm = bid >> 4;
  int row0 = tm * 128, col0 = tn * 64;
  int tid = threadIdx.x;
  int lane = tid & 63;
  int w = tid >> 6;
  int wr = w >> 1, wc = w & 1;              // 2x2 waves: 64x32 each
  int lr = lane & 15, lh = lane >> 4;

  if (tid < 64) sbias[tid] = bsum[col0 + tid];

  int srow = tid >> 2, schunk = tid & 3;
  int gch = (schunk ^ ((srow >> 1) & 3)) * 8;
  const unsigned short* gA0 = Xcur + (size_t)(row0 + srow) * KX + gch;
  const unsigned short* gA1 = Xcur + (size_t)(row0 + 64 + srow) * KX + gch;
  const unsigned short* gB  = Wc  + (size_t)(col0 + srow) * KX + gch;

  int swz = (lh ^ ((lr >> 1) & 3)) * 8;
  int aoff[4], boff[2];
  #pragma unroll
  for (int m = 0; m < 4; ++m) aoff[m] = (wr * 64 + m * 16 + lr) * 32 + swz;
  #pragma unroll
  for (int n = 0; n < 2; ++n) boff[n] = (wc * 32 + n * 16 + lr) * 32 + swz;

  f4_t acc[4][2];
  #pragma unroll
  for (int m = 0; m < 4; ++m)
    #pragma unroll
    for (int n = 0; n < 2; ++n) acc[m][n] = (f4_t){0.f, 0.f, 0.f, 0.f};

#define STAGE(pA, pB, kt) do { \
    gload16(gA0 + (kt) * 32, (pA) + tid * 8); \
    gload16(gA1 + (kt) * 32, (pA) + 2048 + tid * 8); \
    gload16(gB  + (kt) * 32, (pB) + tid * 8); \
  } while (0)

#define COMPUTE(pA, pB) do { \
    bf8_t a_[4], b_[2]; \
    _Pragma("unroll") for (int m = 0; m < 4; ++m) a_[m] = *(const bf8_t*)((pA) + aoff[m]); \
    _Pragma("unroll") for (int n = 0; n < 2; ++n) b_[n] = *(const bf8_t*)((pB) + boff[n]); \
    _Pragma("unroll") for (int m = 0; m < 4; ++m) \
      _Pragma("unroll") for (int n = 0; n < 2; ++n) \
        acc[m][n] = __builtin_amdgcn_mfma_f32_16x16x32_bf16(a_[m], b_[n], acc[m][n], 0, 0, 0); \
  } while (0)

  STAGE(sA0, sB0, 0);
  __syncthreads();
  #pragma unroll 1
  for (int kt = 0; kt < NKT; kt += 2) {
    STAGE(sA1, sB1, kt + 1);
    COMPUTE(sA0, sB0);
    __syncthreads();
    if (kt + 2 < NKT) STAGE(sA0, sB0, kt + 2);
    COMPUTE(sA1, sB1);
    __syncthreads();
  }
#undef STAGE
#undef COMPUTE

  int crow = (lane >> 4) * 4, ccol = lane & 15;
  #pragma unroll
  for (int m = 0; m < 4; ++m)
    #pragma unroll
    for (int n = 0; n < 2; ++n)
      #pragma unroll
      for (int j = 0; j < 4; ++j)
        gtile[wr * 64 + m * 16 + crow + j][wc * 32 + n * 16 + ccol] = acc[m][n][j];
  __syncthreads();

  int row = tid >> 1;
  int q0 = (tid & 1) * 8;
  int grow = row0 + row;
  int ch0 = tn * 16 + q0;
  float4* cb = (float4*)(cbuf + (size_t)grow * HS + ch0);
  float4 cv0 = cb[0], cv1 = cb[1];
  float cold[8] = {cv0.x, cv0.y, cv0.z, cv0.w, cv1.x, cv1.y, cv1.z, cv1.w};
  float c2v[8], h2v[8];
  #pragma unroll
  for (int k = 0; k < 8; ++k) {
    int q = q0 + k;
    float ig = gtile[row][q]      + sbias[q];
    float fg = gtile[row][16 + q] + sbias[16 + q];
    float gg = gtile[row][32 + q] + sbias[32 + q];
    float og = gtile[row][48 + q] + sbias[48 + q];
    float c2 = sigm(fg) * cold[k] + sigm(ig) * tanhf(gg);
    c2v[k] = c2;
    h2v[k] = sigm(og) * tanhf(c2);
  }
  cb[0] = (float4){c2v[0], c2v[1], c2v[2], c2v[3]};
  cb[1] = (float4){c2v[4], c2v[5], c2v[6], c2v[7]};
  u16x8 hx;
  #pragma unroll
  for (int k = 0; k < 8; ++k) hx[k] = f2bf(h2v[k]);
  *(u16x8*)(Xnext + (size_t)grow * KX + 576 + ch0) = hx;
}

// ---- final head for t=63 (512 blocks x 8 rows); Xh = X holding h2(63)
__global__ __launch_bounds__(256) void k_fin(
    const float* __restrict__ data, const float* __restrict__ W_r,
    const float* __restrict__ b_r, const float* __restrict__ Whead,
    const float* __restrict__ bhead, const unsigned short* __restrict__ Xh,
    float* __restrict__ out) {
  head_fin_dev(data, W_r, b_r, Whead, bhead, Xh, out,
               blockIdx.x * 8, T_ - 1, threadIdx.x);
}

extern "C" void kernel_launch(void* const* d_in, const int* in_sizes, int n_in,
                              void* d_out, int out_size, void* d_ws, size_t ws_size,
                              hipStream_t stream) {
  const float* data = (const float*)d_in[0];
  const float* W_r  = (const float*)d_in[2];
  const float* b_r  = (const float*)d_in[3];
  const float* W_e  = (const float*)d_in[4];
  const float* b_e  = (const float*)d_in[5];
  const float* W_ih = (const float*)d_in[6];
  const float* W_hh = (const float*)d_in[7];
  const float* b_ih = (const float*)d_in[8];
  const float* b_hh = (const float*)d_in[9];
  const float* W_p  = (const float*)d_in[10];
  const float* b_p  = (const float*)d_in[11];
  const float* W_p2 = (const float*)d_in[12];
  const float* b_p2 = (const float*)d_in[13];
  const float* W_mu = (const float*)d_in[14];
  const float* b_mu = (const float*)d_in[15];
  const float* W_sd = (const float*)d_in[16];
  const float* b_sd = (const float*)d_in[17];
  const float* W_cr = (const float*)d_in[18];
  const float* b_cr = (const float*)d_in[19];
  float* out = (float*)d_out;

  char* ws = (char*)d_ws;
  float* cbuf  = (float*)(ws);                                // 4 MB
  unsigned short* Xbf0 = (unsigned short*)(ws + (4u  << 20)); // 6.5 MB
  unsigned short* Xbf1 = (unsigned short*)(ws + (11u << 20)); // 6.5 MB
  unsigned short* Wc   = (unsigned short*)(ws + (18u << 20)); // 1.7 MB
  float* bsum  = (float*)(ws + (20u << 20));                  // 4 KB
  float* Whead = (float*)(ws + (20u << 20) + 8192);           // 6.4 KB
  float* bhead = (float*)(ws + (20u << 20) + 16384);          // 20 B
  unsigned short* Web = (unsigned short*)(ws + (20u << 20) + 20480); // 16 KB

  hipMemsetAsync(cbuf, 0, (size_t)N_ * HS * sizeof(float), stream);
  hipMemsetAsync(Xbf0, 0, (size_t)N_ * KX * sizeof(unsigned short), stream);

  k_wcat<<<(GD * KX + GD + ES * HS + 255) / 256, 256, 0, stream>>>(
      W_ih, W_hh, b_ih, b_hh, W_e, Wc, bsum, Web);
  k_head<<<5, 320, 0, stream>>>(W_p, b_p, W_p2, b_p2, W_mu, b_mu, W_sd, b_sd, W_cr, b_cr,
                                Whead, bhead);

  for (int t = 0; t < T_; ++t) {
    unsigned short* Xcur  = (t & 1) ? Xbf1 : Xbf0;
    unsigned short* Xnext = (t & 1) ? Xbf0 : Xbf1;
    k_social<<<512, 256, 0, stream>>>(data, Web, b_e, Xcur, Whead, bhead,
                                      W_r, b_r, out, t);
    k_gemm_lstm<<<512, 256, 0, stream>>>(Xcur, Wc, bsum, cbuf, Xnext);
  }
  // h2(63) lives in Xnext of t=63 -> Xbf0 (t=63 odd)
  k_fin<<<512, 256, 0, stream>>>(data, W_r, b_r, Whead, bhead, Xbf0, out);
}